// Round 8
// baseline (332.163 us; speedup 1.0000x reference)
//
#include <hip/hip_runtime.h>

#define N_  8
#define C_  32
#define H_  224
#define W_  224
#define TM_ 4
#define TA  32   // output tile extent along a (rows)
#define TB  32   // output tile extent along b (cols)
#define NC  4    // planes per interval; 2 intervals per t, 8 intervals total

// R7: single-barrier software pipeline.
//  - tile double-buffered (tile[2][NC][32][33], 33.8 KB): consume(iv) writes
//    tile[iv&1]; write-out(iv) reads it after ONE raw barrier. Next write to
//    the same buffer is at consume(iv+2), gated by barrier(iv+1) -> WAR safe.
//  - raw s_barrier with s_waitcnt lgkmcnt(0) ONLY (no vmcnt drain): the next
//    interval's 64 gathers are issued BEFORE the barrier and stay in flight
//    across barrier + write-out + next geometry, hiding gather latency.
//    (__syncthreads would emit vmcnt(0) and drain the queue - the R0-R6 stall.)
//  - t OUTER (R4/R5 proved n-outer death-spirals the cache: 22x refetch).
// Reference quirk preserved: hx = xs[a], hy = ys[b]; out channel = c*TM + t.
__global__ __launch_bounds__(256, 4) void persp_kernel(
    const float* __restrict__ inp,   // (N, C, H, W)
    const float* __restrict__ wt,    // (TM, C, 8)
    float* __restrict__ out)         // (N, C*TM, H, W)
{
    __shared__ float tile[2][NC][TA][TB + 1];

    const int tid = threadIdx.x;
    const int c   = blockIdx.y;
    const int ta  = blockIdx.x / (W_ / TB);
    const int tb  = blockIdx.x % (W_ / TB);
    const int a0  = ta * TA;
    const int b0  = tb * TB;

    // compute-phase mapping: lane -> a, group -> b
    const int a_off = tid & 31;
    const int bgrp  = tid >> 5;

    const float step = 2.0f / 223.0f;                 // linspace(-1,1,224) step
    const float hx   = -1.0f + (float)(a0 + a_off) * step;   // xs[a]

    // write-phase mapping: lane -> 4 consecutive b (float4), group -> a rows
    const int j4 = (tid & 7) * 4;
    const int iw = tid >> 3;

    const size_t plane   = (size_t)H_ * W_;
    const size_t istride = (size_t)C_ * plane;
    const size_t ostride = (size_t)(C_ * TM_) * plane;

    const float* ibase = inp + (size_t)c * plane;

    int   iA[4], iB[4], iC[4], iD[4];
    float wa[4], wb[4], wc[4], wd[4];

#define GEOM(T)                                                            \
    {                                                                      \
        const float* th_ = wt + ((size_t)(T) * C_ + c) * 8;                \
        const float t0 = th_[0], t1 = th_[1], t2 = th_[2], t3 = th_[3];    \
        const float t4 = th_[4], t5 = th_[5], t6 = th_[6], t7 = th_[7];    \
        _Pragma("unroll")                                                  \
        for (int p = 0; p < 4; ++p) {                                      \
            const int b = b0 + bgrp + 8 * p;                               \
            const float hy = -1.0f + (float)b * step;                      \
            const float w0 = t0 * hx + t1 * hy + t2;                       \
            const float w1 = t3 * hx + t4 * hy + t5;                       \
            const float w2 = t6 * hx + t7 * hy + 1.0f;                     \
            const float xs = w0 / w2;                                      \
            const float ys = w1 / w2;                                      \
            const float x = 0.5f * ((xs + 1.0f) * 222.0f);                 \
            const float y = 0.5f * ((ys + 1.0f) * 222.0f);                 \
            int x0i = (int)floorf(x);                                      \
            int y0i = (int)floorf(y);                                      \
            int x1i = x0i + 1;                                             \
            int y1i = y0i + 1;                                             \
            x0i = min(max(x0i, 0), W_ - 1);                                \
            x1i = min(max(x1i, 0), W_ - 1);                                \
            y0i = min(max(y0i, 0), H_ - 1);                                \
            y1i = min(max(y1i, 0), H_ - 1);                                \
            const float x0f = (float)x0i, x1f = (float)x1i;                \
            const float y0f = (float)y0i, y1f = (float)y1i;                \
            wa[p] = (x1f - x) * (y1f - y);                                 \
            wb[p] = (x1f - x) * (y1f - y0f);                               \
            wc[p] = (x - x0f) * (y1f - y);                                 \
            wd[p] = (x - x0f) * (y - y0f);                                 \
            iA[p] = y0i * W_ + x0i;                                        \
            iB[p] = y1i * W_ + x0i;                                        \
            iC[p] = y0i * W_ + x1i;                                        \
            iD[p] = y1i * W_ + x1i;                                        \
        }                                                                  \
    }

    float ga[NC][4], gb[NC][4], gc[NC][4], gd[NC][4];   // 64 in-flight values

#define ISSUE(NH)                                                          \
    _Pragma("unroll")                                                      \
    for (int nn = 0; nn < NC; ++nn) {                                      \
        const float* ib = ibase + (size_t)((NH) * NC + nn) * istride;      \
        _Pragma("unroll")                                                  \
        for (int p = 0; p < 4; ++p) {                                      \
            ga[nn][p] = ib[iA[p]];                                         \
            gb[nn][p] = ib[iB[p]];                                         \
            gc[nn][p] = ib[iC[p]];                                         \
            gd[nn][p] = ib[iD[p]];                                         \
        }                                                                  \
    }

    GEOM(0);
    ISSUE(0);

#pragma unroll
    for (int iv = 0; iv < 2 * TM_; ++iv) {
        const int t   = iv >> 1;
        const int nh  = iv & 1;
        const int buf = iv & 1;

        // consume current batch into tile[buf] (vmcnt waits happen here)
#pragma unroll
        for (int nn = 0; nn < NC; ++nn)
#pragma unroll
            for (int p = 0; p < 4; ++p)
                tile[buf][nn][a_off][bgrp + 8 * p] =
                    wa[p] * ga[nn][p] + wb[p] * gb[nn][p] +
                    wc[p] * gc[nn][p] + wd[p] * gd[nn][p];

        // prefetch next interval's 64 gathers BEFORE the barrier
        if (iv < 2 * TM_ - 1) {
            if (nh == 1) GEOM(t + 1);
            ISSUE((iv + 1) & 1);
        }

        // raw barrier: drain LDS writes only, keep global loads in flight
        asm volatile("s_waitcnt lgkmcnt(0)" ::: "memory");
        __builtin_amdgcn_s_barrier();
        asm volatile("" ::: "memory");   // block hoisting ds_reads above barrier

        // coalesced float4 write-out: lanes along b
        float* ob = out + ((size_t)(c * TM_ + t)) * plane
                        + (size_t)(a0 + iw) * W_ + (b0 + j4);
#pragma unroll
        for (int nn = 0; nn < NC; ++nn) {
            const int n = nh * NC + nn;
            float4 v;
            v.x = tile[buf][nn][iw][j4 + 0];
            v.y = tile[buf][nn][iw][j4 + 1];
            v.z = tile[buf][nn][iw][j4 + 2];
            v.w = tile[buf][nn][iw][j4 + 3];
            *reinterpret_cast<float4*>(ob + (size_t)n * ostride) = v;
        }
    }
#undef GEOM
#undef ISSUE
}

extern "C" void kernel_launch(void* const* d_in, const int* in_sizes, int n_in,
                              void* d_out, int out_size, void* d_ws, size_t ws_size,
                              hipStream_t stream) {
    const float* inp = (const float*)d_in[0];   // (8,32,224,224) f32
    const float* wt  = (const float*)d_in[1];   // (4,32,8) f32
    float* out = (float*)d_out;                 // (8,128,224,224) f32

    dim3 grid((H_ / TA) * (W_ / TB), C_);       // 49 x 32 = 1568 blocks
    persp_kernel<<<grid, 256, 0, stream>>>(inp, wt, out);
}